// Round 9
// baseline (323.565 us; speedup 1.0000x reference)
//
#include <hip/hip_runtime.h>
#include <hip/hip_bf16.h>

// GraphSAGE 2-layer. Project-then-aggregate (aggregation is linear):
//   ycomb = x @ [W1l|W1r]^T   (bf16 MFMA; A+B via global_load_lds in 1-KB
//                              per-row chunks for DRAM page locality)
//   CSR build (once): counting-sort edges by tgt
//   h     = csr_mean(ycomb[:, :32]) + b1l + ycomb[:,32:]
//   ycomb = h @ [W2l|W2r]^T
//   out   = log_softmax(relu(csr_mean(ycomb[:, :32]) + b2l + ycomb[:,32:]))

typedef __attribute__((ext_vector_type(8))) __bf16 bf16x8;
typedef __attribute__((ext_vector_type(4))) float f32x4;

constexpr int K1 = 1433;
constexpr int KP1 = 1536;  // B pad (bf16): 6*256, no B guards anywhere
constexpr int BK2 = 256;   // floats per k-step = 1 KB per row per step
constexpr int NS2 = 6;     // 6*256 = 1536
constexpr int BM2 = 32;    // rows per block (100000/32 = 3125 exact)

__device__ __forceinline__ void gload_lds16(const void* g, void* l) {
  __builtin_amdgcn_global_load_lds(
      reinterpret_cast<const __attribute__((address_space(1))) void*>(
          reinterpret_cast<uintptr_t>(g)),
      reinterpret_cast<__attribute__((address_space(3))) void*>(
          reinterpret_cast<uintptr_t>(l)),
      16, 0, 0);
}

__device__ __forceinline__ bf16x8 cvt8(const float4 lo, const float4 hi) {
  bf16x8 r;
  r[0] = (__bf16)lo.x; r[1] = (__bf16)lo.y;
  r[2] = (__bf16)lo.z; r[3] = (__bf16)lo.w;
  r[4] = (__bf16)hi.x; r[5] = (__bf16)hi.y;
  r[6] = (__bf16)hi.z; r[7] = (__bf16)hi.w;
  return r;
}

// Convert [W_l; W_r] (each 32 x K fp32) into WB[64][KP] bf16, zero-padded.
__global__ __launch_bounds__(256) void conv_w(const float* __restrict__ Wl,
                                              const float* __restrict__ Wr,
                                              __bf16* __restrict__ out, int K,
                                              int KP) {
  const int t = blockIdx.x * 256 + threadIdx.x;
  if (t >= 64 * KP) return;
  const int c = t / KP, k = t - c * KP;
  float v = 0.0f;
  if (k < K) v = (c < 32) ? Wl[(long)c * K + k] : Wr[(long)(c - 32) * K + k];
  out[t] = (__bf16)v;
}

// Y[N][64] = X[N][1433] @ WB[64][1536]^T.
// DRAM-locality-first: every A gload_lds instruction reads ONE row's 1-KB
// contiguous chunk (64 lanes x 16 B lane-linear, low-3-bit chunk XOR only).
// 4 waves (2x2); wave computes 16 rows x 32 cols. 128 KB LDS, 1 block/CU.
// Counted vmcnt(16) keeps next stage in flight across raw barriers (T4).
__global__ __launch_bounds__(256) void gemm_big(const float* __restrict__ X,
                                                const __bf16* __restrict__ WB,
                                                float* __restrict__ Y,
                                                int Nrows) {
  __shared__ float ldsA[2][BM2][BK2];    // 2 x 32 KB
  __shared__ __bf16 ldsB[2][64][BK2];    // 2 x 32 KB
  const int tid = threadIdx.x;
  const int w = tid >> 6, l = tid & 63;
  const int lr = l & 15, lg = l >> 4;
  const int wr = w >> 1, wc = w & 1;     // wave grid 2 (rows) x 2 (cols)
  const int row0 = blockIdx.x * BM2;

  // ---- staging sources ----
  // A: wave w, instr i (<8) -> block-row ar = w*8+i (ar&7 == i).
  //    lane l reads 16-B chunk (l ^ i) of the row's current 1-KB k-window;
  //    LDS dest row ar is written lane-linear -> LDS chunk p holds global
  //    chunk p^(ar&7)  (read side XORs the same).
  const float* pA[8];
#pragma unroll
  for (int i = 0; i < 8; ++i) {
    long r = (long)row0 + w * 8 + i;
    if (r >= Nrows) r = Nrows - 1;
    pA[i] = X + r * (long)K1 + ((l ^ i) << 2);
  }
  const float* const pAmax = X + (size_t)Nrows * K1 - 4;  // stay inside X
  // B: wave w, instr j (<8) -> rows 2J, 2J+1 (J = w*8+j); lanes 0-31 row 2J,
  //    lanes 32-63 row 2J+1; chunk (l&31) ^ (brow&7) of the 512-B k-window.
  const __bf16* pB[8];
#pragma unroll
  for (int j = 0; j < 8; ++j) {
    const int J = w * 8 + j;
    const int brow = 2 * J + (l >> 5);
    pB[j] = WB + (long)brow * KP1 + (((l & 31) ^ (brow & 7)) << 3);
  }

  auto stage = [&](int s, int buf) {
    const int k0 = s * BK2;
#pragma unroll
    for (int i = 0; i < 8; ++i) {
      const float* g = pA[i] + k0;
      if (g > pAmax) g = pAmax;  // finite garbage * B-zero-pad = 0
      gload_lds16(g, &ldsA[buf][w * 8 + i][0]);
    }
#pragma unroll
    for (int j = 0; j < 8; ++j) {
      gload_lds16(pB[j] + k0, &ldsB[buf][2 * (w * 8 + j)][0]);
    }
  };

  f32x4 acc[2];
#pragma unroll
  for (int ct = 0; ct < 2; ++ct) acc[ct] = (f32x4){0.f, 0.f, 0.f, 0.f};

  const int swz = (lr & 7) << 4;  // read-side XOR (row&7 == lr&7: bases %8==0)

  stage(0, 0);
#pragma unroll 1
  for (int s = 0; s < NS2; ++s) {
    const int buf = s & 1;
    if (s + 1 < NS2) {
      stage(s + 1, buf ^ 1);  // 32 outstanding/wave
      // retire the oldest 16 (= stage(s)); keep stage(s+1) in flight
      asm volatile("s_waitcnt vmcnt(16)" ::: "memory");
    } else {
      asm volatile("s_waitcnt vmcnt(0)" ::: "memory");
    }
    __builtin_amdgcn_s_barrier();       // all waves: their stage(s) retired
    __builtin_amdgcn_sched_barrier(0);  // fence: no ds_read hoisted above
    // ---- compute from LDS only ----
#pragma unroll
    for (int ks = 0; ks < 8; ++ks) {
      const char* arow = (const char*)&ldsA[buf][wr * 16 + lr][0];
      const int b0 = ks * 128 + lg * 32;
      const float4 u = *reinterpret_cast<const float4*>(arow + (b0 ^ swz));
      const float4 v =
          *reinterpret_cast<const float4*>(arow + ((b0 + 16) ^ swz));
      const bf16x8 af = cvt8(u, v);
#pragma unroll
      for (int ct = 0; ct < 2; ++ct) {
        const char* bp =
            (const char*)&ldsB[buf][wc * 32 + ct * 16 + lr][0];
        const bf16x8 bf = *reinterpret_cast<const bf16x8*>(
            bp + ((ks * 64 + lg * 16) ^ swz));
        acc[ct] =
            __builtin_amdgcn_mfma_f32_16x16x32_bf16(af, bf, acc[ct], 0, 0, 0);
      }
    }
    __builtin_amdgcn_sched_barrier(0);  // all reads issued before barrier
    __builtin_amdgcn_s_barrier();       // reads of buf done before re-stage
  }

  // D layout: col = lane&15 (lr), row = lg*4 + reg j
#pragma unroll
  for (int j = 0; j < 4; ++j) {
    const long R = (long)row0 + wr * 16 + lg * 4 + j;
    if (R < Nrows) {
#pragma unroll
      for (int ct = 0; ct < 2; ++ct)
        Y[R * 64 + wc * 32 + ct * 16 + lr] = acc[ct][j];
    }
  }
}

// Y[N][64] = X[N][32] @ WB[64][32]^T, single k-step.
__global__ __launch_bounds__(256) void gemm_small(const float* __restrict__ X,
                                                  const __bf16* __restrict__ WB,
                                                  float* __restrict__ Y,
                                                  int Nrows) {
  const int tid = threadIdx.x;
  const int w = tid >> 6, l = tid & 63;
  const int lr = l & 15, lg = l >> 4;
  const long rowbase = (long)blockIdx.x * 64 + (long)w * 16;
  long r0 = rowbase + lr;
  if (r0 >= Nrows) r0 = Nrows - 1;
  const float* px = X + r0 * 32 + lg * 8;
  const __bf16* pw = WB + lr * 32 + lg * 8;

  const float4 lo = *reinterpret_cast<const float4*>(px);
  const float4 hi = *reinterpret_cast<const float4*>(px + 4);
  const bf16x8 af = cvt8(lo, hi);
  f32x4 acc[4];
#pragma unroll
  for (int j = 0; j < 4; ++j) acc[j] = (f32x4){0.f, 0.f, 0.f, 0.f};
#pragma unroll
  for (int t = 0; t < 4; ++t) {
    const bf16x8 bf = *reinterpret_cast<const bf16x8*>(pw + t * 16 * 32);
    acc[t] = __builtin_amdgcn_mfma_f32_16x16x32_bf16(af, bf, acc[t], 0, 0, 0);
  }
#pragma unroll
  for (int j = 0; j < 4; ++j) {
    const long R = rowbase + lg * 4 + j;
    if (R < Nrows) {
#pragma unroll
      for (int ct = 0; ct < 4; ++ct) Y[R * 64 + ct * 16 + lr] = acc[ct][j];
    }
  }
}

// ---------------- CSR build: counting sort edges by tgt ----------------

__global__ __launch_bounds__(256) void hist_deg(const int* __restrict__ ei,
                                                int* __restrict__ deg, int E) {
  const int e = blockIdx.x * 256 + threadIdx.x;
  if (e < E) atomicAdd(&deg[ei[E + e]], 1);
}

__global__ __launch_bounds__(256) void scan_tilesum(const int* __restrict__ deg,
                                                    int* __restrict__ tileSum,
                                                    int n) {
  __shared__ int s[256];
  const int b = blockIdx.x, t = threadIdx.x;
  const int base = b * 2048 + t * 8;
  int v = 0;
#pragma unroll
  for (int j = 0; j < 8; ++j) {
    const int i = base + j;
    if (i < n) v += deg[i];
  }
  s[t] = v;
  __syncthreads();
  for (int d = 128; d > 0; d >>= 1) {
    if (t < d) s[t] += s[t + d];
    __syncthreads();
  }
  if (t == 0) tileSum[b] = s[0];
}

__global__ __launch_bounds__(64) void scan_tileoff(const int* __restrict__ tileSum,
                                                   int* __restrict__ tileOff,
                                                   int nT) {
  const int l = threadIdx.x;
  const int v = (l < nT) ? tileSum[l] : 0;
  int inc = v;
#pragma unroll
  for (int d = 1; d < 64; d <<= 1) {
    const int o = __shfl_up(inc, d);
    if (l >= d) inc += o;
  }
  if (l < nT) tileOff[l] = inc - v;
}

__global__ __launch_bounds__(256) void scan_offsets(const int* __restrict__ deg,
                                                    const int* __restrict__ tileOff,
                                                    int* __restrict__ off, int n) {
  __shared__ int warpTot[4];
  const int b = blockIdx.x, t = threadIdx.x;
  const int base = b * 2048 + t * 8;
  int v[8];
  int s = 0;
#pragma unroll
  for (int j = 0; j < 8; ++j) {
    const int i = base + j;
    v[j] = (i < n) ? deg[i] : 0;
    s += v[j];
  }
  const int l = t & 63, w = t >> 6;
  int inc = s;
#pragma unroll
  for (int d = 1; d < 64; d <<= 1) {
    const int o = __shfl_up(inc, d);
    if (l >= d) inc += o;
  }
  if (l == 63) warpTot[w] = inc;
  __syncthreads();
  int wo = 0;
  for (int k = 0; k < w; ++k) wo += warpTot[k];
  int ex = wo + (inc - s) + tileOff[b];
#pragma unroll
  for (int j = 0; j < 8; ++j) {
    const int i = base + j;
    if (i < n) {
      off[i] = ex;
      ex += v[j];
    }
  }
}

__global__ __launch_bounds__(256) void scatter_src(const int* __restrict__ ei,
                                                   const int* __restrict__ off,
                                                   int* __restrict__ fill,
                                                   int* __restrict__ ssrc,
                                                   int E) {
  const int e = blockIdx.x * 256 + threadIdx.x;
  if (e < E) {
    const int t = ei[E + e];
    const int p = off[t] + atomicAdd(&fill[t], 1);
    ssrc[p] = ei[e];
  }
}

// ---------------- fused aggregation ----------------
template <int FINAL>
__global__ __launch_bounds__(256) void agg_fused(
    const int* __restrict__ off, const int* __restrict__ deg,
    const int* __restrict__ ssrc, const float* __restrict__ Y,
    const float* __restrict__ bias, float* __restrict__ out, int N) {
  const int t = blockIdx.x * 256 + threadIdx.x;
  const int i = t >> 5, c = t & 31;
  if (i >= N) return;
  const int st = off[i], d = deg[i];
  float acc = 0.0f;
  int e = 0;
  for (; e + 4 <= d; e += 4) {
    const int s0 = ssrc[st + e + 0];
    const int s1 = ssrc[st + e + 1];
    const int s2 = ssrc[st + e + 2];
    const int s3 = ssrc[st + e + 3];
    acc += Y[(long)s0 * 64 + c] + Y[(long)s1 * 64 + c] +
           Y[(long)s2 * 64 + c] + Y[(long)s3 * 64 + c];
  }
  for (; e < d; ++e) acc += Y[(long)ssrc[st + e] * 64 + c];
  const float mean = acc / fmaxf((float)d, 1.0f);
  float v = mean + bias[c] + Y[(long)i * 64 + 32 + c];
  if (FINAL) {
    v = fmaxf(v, 0.0f);
    float m = v;
#pragma unroll
    for (int dd = 16; dd >= 1; dd >>= 1) m = fmaxf(m, __shfl_xor(m, dd));
    const float ex = __expf(v - m);
    float s = ex;
#pragma unroll
    for (int dd = 16; dd >= 1; dd >>= 1) s += __shfl_xor(s, dd);
    out[(long)i * 32 + c] = (v - m) - __logf(s);
  } else {
    out[(long)i * 32 + c] = v;
  }
}

extern "C" void kernel_launch(void* const* d_in, const int* in_sizes, int n_in,
                              void* d_out, int out_size, void* d_ws,
                              size_t ws_size, hipStream_t stream) {
  const float* x = (const float*)d_in[0];
  const int* ei = (const int*)d_in[1];
  const float* W1l = (const float*)d_in[2];
  const float* b1l = (const float*)d_in[3];
  const float* W1r = (const float*)d_in[4];
  const float* W2l = (const float*)d_in[5];
  const float* b2l = (const float*)d_in[6];
  const float* W2r = (const float*)d_in[7];
  float* out = (float*)d_out;

  const int N = in_sizes[0] / K1;
  const int E = in_sizes[1] / 2;
  const int nTiles = (N + 2047) / 2048;

  char* ws = (char*)d_ws;
  size_t o = 0;
  auto alloc = [&](size_t bytes) {
    void* p = ws + o;
    o += (bytes + 255) & ~(size_t)255;
    return p;
  };
  float* ycomb = (float*)alloc((size_t)N * 64 * 4);
  float* h = (float*)alloc((size_t)N * 32 * 4);
  __bf16* wb1 = (__bf16*)alloc((size_t)64 * KP1 * 2);
  __bf16* wb2 = (__bf16*)alloc((size_t)64 * 32 * 2);
  int* deg = (int*)alloc((size_t)N * 4);
  int* off = (int*)alloc((size_t)N * 4);
  int* fill = (int*)alloc((size_t)N * 4);
  int* ssrc = (int*)alloc((size_t)E * 4);
  int* tileSum = (int*)alloc(64 * 4);
  int* tileOff = (int*)alloc(64 * 4);

  conv_w<<<(64 * KP1 + 255) / 256, 256, 0, stream>>>(W1l, W1r, wb1, K1, KP1);
  conv_w<<<(64 * 32 + 255) / 256, 256, 0, stream>>>(W2l, W2r, wb2, 32, 32);
  (void)hipMemsetAsync(deg, 0, (size_t)N * 4, stream);
  (void)hipMemsetAsync(fill, 0, (size_t)N * 4, stream);
  hist_deg<<<(E + 255) / 256, 256, 0, stream>>>(ei, deg, E);
  scan_tilesum<<<nTiles, 256, 0, stream>>>(deg, tileSum, N);
  scan_tileoff<<<1, 64, 0, stream>>>(tileSum, tileOff, nTiles);
  scan_offsets<<<nTiles, 256, 0, stream>>>(deg, tileOff, off, N);
  scatter_src<<<(E + 255) / 256, 256, 0, stream>>>(ei, off, fill, ssrc, E);

  // Layer 1
  gemm_big<<<(N + BM2 - 1) / BM2, 256, 0, stream>>>(x, wb1, ycomb, N);
  agg_fused<0><<<(N * 32 + 255) / 256, 256, 0, stream>>>(off, deg, ssrc, ycomb,
                                                         b1l, h, N);
  // Layer 2
  gemm_small<<<(N + 63) / 64, 256, 0, stream>>>(h, wb2, ycomb, N);
  agg_fused<1><<<(N * 32 + 255) / 256, 256, 0, stream>>>(off, deg, ssrc, ycomb,
                                                         b2l, out, N);
}